// Round 4
// baseline (133.398 us; speedup 1.0000x reference)
//
#include <hip/hip_runtime.h>
#include <hip/hip_bf16.h>
#include <cstdint>

// Problem: B=64, D=1024, H=1024.
// act columns (6144): [0,1024) i_g | [1024,2048) f_g | [2048,3072) o_g
//                     [3072,4096) q | [4096,5120) k  | [5120,6144) v

#define NCOL 6144

typedef __attribute__((ext_vector_type(8))) short short8;
typedef __attribute__((ext_vector_type(4))) float f32x4;
typedef __attribute__((ext_vector_type(4))) unsigned short u16x4;

static __device__ __forceinline__ unsigned short f2b(float f) {
    union { float f; uint32_t u; } v; v.f = f;
    uint32_t r = (v.u + 0x7FFFu + ((v.u >> 16) & 1u)) >> 16;  // RNE
    return (unsigned short)r;
}

// ---------------- Kernel P: fused projections + activations ----------------
// grid: 96 blocks (one per 64-col tile), 256 threads = 4 waves.
// Block computes full-K 64 cols x 64 batches via bf16 MFMA, double-buffered
// LDS with register prefetch, then applies bias+activation and writes act.
__global__ __launch_bounds__(256) void proj_act_kernel(
    const float* __restrict__ input, const float* __restrict__ hvec,
    const float* __restrict__ w_ih, const float* __restrict__ w_hh,
    const float* __restrict__ wq, const float* __restrict__ wk,
    const float* __restrict__ wv, const float* __restrict__ bias,
    const float* __restrict__ wq_b, const float* __restrict__ wk_b,
    const float* __restrict__ wv_b, float* __restrict__ act)
{
    int ct = blockIdx.x;            // 0..95
    int jbase = ct * 64;
    int o = jbase >> 10;            // 0..5: which output segment
    int jloc = jbase & 1023;

    const float* Wm   = (o < 3) ? w_ih : (o == 3) ? wq : (o == 4) ? wk : wv;
    const float* bsel = (o < 3) ? (bias + jbase)
                                : ((o == 3) ? wq_b : (o == 4) ? wk_b : wv_b) + jloc;
    int wrow  = (o < 3) ? o * 1024 + jloc : jloc;
    int niter = (o < 3) ? 16 : 8;   // chunks of K=128

    // double-buffered bf16 tiles, +8 pad (272B row stride)
    __shared__ unsigned short Als[2][64][136];
    __shared__ unsigned short Bls[2][64][136];

    int tid = threadIdx.x;
    int r0 = tid >> 5;              // staging base row (+8*i)
    int k4 = (tid & 31) << 2;       // k offset 0..124

    f32x4 ra[8], rb[8];

    // prefetch chunk 0 (always from input / Wm)
    #pragma unroll
    for (int i = 0; i < 8; ++i)
        ra[i] = *(const f32x4*)&input[(size_t)(r0 + 8 * i) * 1024 + k4];
    #pragma unroll
    for (int i = 0; i < 8; ++i)
        rb[i] = *(const f32x4*)&Wm[(size_t)(wrow + r0 + 8 * i) * 1024 + k4];
    #pragma unroll
    for (int i = 0; i < 8; ++i) {
        u16x4 u; u[0]=f2b(ra[i][0]); u[1]=f2b(ra[i][1]); u[2]=f2b(ra[i][2]); u[3]=f2b(ra[i][3]);
        *(u16x4*)&Als[0][r0 + 8 * i][k4] = u;
    }
    #pragma unroll
    for (int i = 0; i < 8; ++i) {
        u16x4 u; u[0]=f2b(rb[i][0]); u[1]=f2b(rb[i][1]); u[2]=f2b(rb[i][2]); u[3]=f2b(rb[i][3]);
        *(u16x4*)&Bls[0][r0 + 8 * i][k4] = u;
    }
    __syncthreads();

    int lane = tid & 63;
    int w    = tid >> 6;            // wave -> col group (w*16)
    int cn16 = lane & 15;
    int kg   = lane >> 4;           // 0..3

    f32x4 acc[4];
    #pragma unroll
    for (int m = 0; m < 4; ++m) { acc[m][0]=0.f; acc[m][1]=0.f; acc[m][2]=0.f; acc[m][3]=0.f; }

    for (int it = 0; it < niter; ++it) {
        // issue next chunk's global loads before this chunk's MFMAs
        if (it + 1 < niter) {
            int it2 = it + 1;
            const float* sA = input; const float* sB = Wm; int koff = it2 * 128;
            if (o < 3 && it2 >= 8) { sA = hvec; sB = w_hh; koff = (it2 - 8) * 128; }
            #pragma unroll
            for (int i = 0; i < 8; ++i)
                ra[i] = *(const f32x4*)&sA[(size_t)(r0 + 8 * i) * 1024 + koff + k4];
            #pragma unroll
            for (int i = 0; i < 8; ++i)
                rb[i] = *(const f32x4*)&sB[(size_t)(wrow + r0 + 8 * i) * 1024 + koff + k4];
        }

        int cb = it & 1;
        #pragma unroll
        for (int ks = 0; ks < 4; ++ks) {
            int kb = ks * 32 + kg * 8;
            short8 bf = *(const short8*)&Bls[cb][w * 16 + cn16][kb];
            #pragma unroll
            for (int m = 0; m < 4; ++m) {
                short8 af = *(const short8*)&Als[cb][m * 16 + cn16][kb];
                acc[m] = __builtin_amdgcn_mfma_f32_16x16x32_bf16(af, bf, acc[m], 0, 0, 0);
            }
        }

        if (it + 1 < niter) {
            int nb = (it + 1) & 1;
            #pragma unroll
            for (int i = 0; i < 8; ++i) {
                u16x4 u; u[0]=f2b(ra[i][0]); u[1]=f2b(ra[i][1]); u[2]=f2b(ra[i][2]); u[3]=f2b(ra[i][3]);
                *(u16x4*)&Als[nb][r0 + 8 * i][k4] = u;
            }
            #pragma unroll
            for (int i = 0; i < 8; ++i) {
                u16x4 u; u[0]=f2b(rb[i][0]); u[1]=f2b(rb[i][1]); u[2]=f2b(rb[i][2]); u[3]=f2b(rb[i][3]);
                *(u16x4*)&Bls[nb][r0 + 8 * i][k4] = u;
            }
        }
        __syncthreads();
    }

    // epilogue: bias + activation, direct act write.
    // D layout: col = lane&15 (-> jbase + w*16 + cn16), row = kg*4 + reg (+m*16)
    float bcol = bsel[w * 16 + cn16];
    #pragma unroll
    for (int m = 0; m < 4; ++m) {
        #pragma unroll
        for (int r = 0; r < 4; ++r) {
            int b = m * 16 + kg * 4 + r;
            float v = acc[m][r] + bcol;
            if (o < 2)       v = expf(v);                 // i_g, f_g
            else if (o == 2) v = 1.f / (1.f + expf(-v));  // o_g
            act[(size_t)b * NCOL + jbase + w * 16 + cn16] = v;
        }
    }
}

// ---------------- Kernel U: c_new = f*c + (i*v)*k, fused q-weighted row sums -
// grid: (16 row-tiles of 64, 64 batches), 256 threads, 4 cols/thread.
__global__ __launch_bounds__(256) void update_kernel(
    const float* __restrict__ c_in, const float* __restrict__ act,
    float* __restrict__ c_out, float* __restrict__ hpart)
{
    int t = blockIdx.x;            // 0..15
    int b = blockIdx.y;            // 0..63
    int tid = threadIdx.x;
    const float* arow = act + (size_t)b * NCOL;

    __shared__ float fs[64], ivs[64], qvs[64];
    if (tid < 64) {
        int hrow = t * 64 + tid;
        fs[tid]  = arow[1024 + hrow];
        ivs[tid] = arow[hrow] * arow[5120 + hrow];
        qvs[tid] = arow[3072 + hrow];
    }
    int col = tid * 4;
    f32x4 k4 = *(const f32x4*)&arow[4096 + col];
    __syncthreads();

    f32x4 acc; acc[0]=0.f; acc[1]=0.f; acc[2]=0.f; acc[3]=0.f;
    size_t base = ((size_t)b * 1024 + (size_t)t * 64) * 1024 + col;

    #pragma unroll 8
    for (int hh = 0; hh < 64; ++hh) {
        f32x4 c4 = __builtin_nontemporal_load((const f32x4*)(c_in + base + (size_t)hh * 1024));
        float f = fs[hh], iv = ivs[hh], qv = qvs[hh];
        f32x4 cn = f * c4 + iv * k4;
        __builtin_nontemporal_store(cn, (f32x4*)(c_out + base + (size_t)hh * 1024));
        acc += qv * cn;
    }
    *(f32x4*)&hpart[((size_t)b * 16 + t) * 1024 + col] = acc;
}

// ---------------- Kernel R: h_new = o_g * sum_t hpart ----------------
__global__ __launch_bounds__(256) void readout_kernel(
    const float* __restrict__ hpart, const float* __restrict__ act,
    float* __restrict__ h_new)
{
    int idx = blockIdx.x * 256 + threadIdx.x;   // 0..65536
    int b = idx >> 10, j = idx & 1023;
    float s = 0.f;
    #pragma unroll
    for (int t = 0; t < 16; ++t)
        s += hpart[((size_t)b * 16 + t) * 1024 + j];
    h_new[idx] = act[(size_t)b * NCOL + 2048 + j] * s;
}

extern "C" void kernel_launch(void* const* d_in, const int* in_sizes, int n_in,
                              void* d_out, int out_size, void* d_ws, size_t ws_size,
                              hipStream_t stream)
{
    (void)in_sizes; (void)n_in; (void)out_size; (void)ws_size;
    const float* input = (const float*)d_in[0];   // [64,1024]
    const float* hvec  = (const float*)d_in[1];   // [64,1024]
    const float* c_in  = (const float*)d_in[2];   // [64,1024,1024]
    const float* w_ih  = (const float*)d_in[3];   // [3072,1024]
    const float* w_hh  = (const float*)d_in[4];   // [3072,1024]
    const float* bias  = (const float*)d_in[5];   // [3072]
    const float* wq_w  = (const float*)d_in[6];   // [1024,1024]
    const float* wq_b  = (const float*)d_in[7];
    const float* wk_w  = (const float*)d_in[8];
    const float* wk_b  = (const float*)d_in[9];
    const float* wv_w  = (const float*)d_in[10];
    const float* wv_b  = (const float*)d_in[11];

    float* out   = (float*)d_out;
    float* h_new = out;                 // [64,1024]
    float* c_new = out + 64 * 1024;     // [64,1024,1024]

    float* ws    = (float*)d_ws;
    float* act   = ws;                              // 64*6144 floats
    float* hpart = act + (size_t)64 * NCOL;         // 64*16*1024 floats

    proj_act_kernel<<<96, 256, 0, stream>>>(input, hvec, w_ih, w_hh,
                                            wq_w, wk_w, wv_w, bias,
                                            wq_b, wk_b, wv_b, act);
    update_kernel<<<dim3(16, 64), 256, 0, stream>>>(c_in, act, c_new, hpart);
    readout_kernel<<<(64 * 1024) / 256, 256, 0, stream>>>(hpart, act, h_new);
}